// Round 1
// baseline (61.091 us; speedup 1.0000x reference)
//
#include <hip/hip_runtime.h>

#define POOL 7
#define NSAMP 2
#define CCH 256
#define HH 100
#define WW 100
#define NN 8

static constexpr float SCALE = 0.125f;

// ---- Transpose NCHW -> NHWC (per n: (C, H*W) -> (H*W, C)) ----
__global__ __launch_bounds__(256) void transpose_nchw_to_nhwc(
    const float* __restrict__ x, float* __restrict__ xt)
{
    __shared__ float tile[32][33];
    const int HW = HH * WW;
    int n   = blockIdx.z;
    int hw0 = blockIdx.x * 32;
    int c0  = blockIdx.y * 32;          // c0+31 <= 255 always (C=256, grid.y=8)
    const float* xn = x + (size_t)n * CCH * HW;
    float* xtn      = xt + (size_t)n * HW * CCH;
    int tx = threadIdx.x & 31;
    int ty = threadIdx.x >> 5;          // 0..7

    #pragma unroll
    for (int i = 0; i < 32; i += 8) {
        int cc = c0 + ty + i;
        int hh = hw0 + tx;
        if (hh < HW) tile[ty + i][tx] = xn[(size_t)cc * HW + hh];
    }
    __syncthreads();
    #pragma unroll
    for (int i = 0; i < 32; i += 8) {
        int hh = hw0 + ty + i;
        int cc = c0 + tx;
        if (hh < HW) xtn[(size_t)hh * CCH + cc] = tile[tx][ty + i];
    }
}

// ---- ROI Align main kernel ----
// One block per (roi, py); 256 threads = channels. NHWC=true reads the
// transposed tensor (coalesced across channels), false reads NCHW directly.
template <bool NHWC>
__global__ __launch_bounds__(256) void roi_align_kernel(
    const float* __restrict__ xin, const float* __restrict__ rois,
    float* __restrict__ out, int nwg)
{
    // chunked bijective XCD swizzle: all bins of a ROI land on one XCD
    int blk = blockIdx.x;
    int wg  = ((nwg & 7) == 0) ? ((blk & 7) * (nwg >> 3) + (blk >> 3)) : blk;
    int r  = wg / POOL;
    int py = wg % POOL;

    __shared__ int   s_xlo[POOL * NSAMP], s_xhi[POOL * NSAMP];
    __shared__ float s_wx1[POOL * NSAMP], s_wx2[POOL * NSAMP];
    __shared__ int   s_ylo[NSAMP], s_yhi[NSAMP];
    __shared__ float s_wy1[NSAMP], s_wy2[NSAMP];

    float r0 = rois[r * 5 + 0];
    float x1 = rois[r * 5 + 1];
    float y1 = rois[r * 5 + 2];
    float x2 = rois[r * 5 + 3];
    float y2 = rois[r * 5 + 4];
    int   n  = (int)r0;
    float sx0 = x1 * SCALE - 0.5f;
    float sy0 = y1 * SCALE - 0.5f;
    float bw  = (x2 * SCALE - 0.5f - sx0) / (float)POOL;
    float bh  = (y2 * SCALE - 0.5f - sy0) / (float)POOL;

    int t = threadIdx.x;
    if (t < POOL * NSAMP + NSAMP) {      // 16 threads build the tap tables
        float c, L;
        if (t < POOL * NSAMP) {
            int px = t >> 1, sxi = t & 1;
            c = sx0 + ((float)px + ((float)sxi + 0.5f) / (float)NSAMP) * bw;
            L = (float)WW;
        } else {
            int syi = t - POOL * NSAMP;
            c = sy0 + ((float)py + ((float)syi + 0.5f) / (float)NSAMP) * bh;
            L = (float)HH;
        }
        bool  valid = (c > -1.0f) && (c < L);
        float cc = fminf(fmaxf(c, 0.0f), L - 1.0f);
        int   Li = (int)L;
        int   lo = (int)floorf(cc);
        if (lo > Li - 1) lo = Li - 1;
        int   hi = lo + 1;
        if (hi > Li - 1) hi = Li - 1;
        float fr = cc - (float)lo;
        float w1 = valid ? 1.0f - fr : 0.0f;
        float w2 = valid ? fr : 0.0f;
        if (t < POOL * NSAMP) {
            s_xlo[t] = lo; s_xhi[t] = hi; s_wx1[t] = w1; s_wx2[t] = w2;
        } else {
            int k = t - POOL * NSAMP;
            s_ylo[k] = lo; s_yhi[k] = hi; s_wy1[k] = w1; s_wy2[k] = w2;
        }
    }
    __syncthreads();

    int c = t;                            // channel index (C == 256 == blockDim)
    float acc[POOL];
    #pragma unroll
    for (int px = 0; px < POOL; ++px) acc[px] = 0.0f;

    const float* xb;
    if (NHWC) xb = xin + ((size_t)n * HH * WW) * CCH + c;
    else      xb = xin + ((size_t)n * CCH + c) * (HH * WW);

    #pragma unroll
    for (int syi = 0; syi < NSAMP; ++syi) {
        int   yl  = s_ylo[syi], yh = s_yhi[syi];
        float wy1 = s_wy1[syi], wy2 = s_wy2[syi];
        #pragma unroll
        for (int px = 0; px < POOL; ++px) {
            float a = 0.0f;
            #pragma unroll
            for (int sxi = 0; sxi < NSAMP; ++sxi) {
                int   k   = px * NSAMP + sxi;
                int   xl  = s_xlo[k], xh = s_xhi[k];
                float wx1 = s_wx1[k], wx2 = s_wx2[k];
                float vll, vlh, vhl, vhh;
                if (NHWC) {
                    vll = xb[(size_t)(yl * WW + xl) * CCH];
                    vlh = xb[(size_t)(yl * WW + xh) * CCH];
                    vhl = xb[(size_t)(yh * WW + xl) * CCH];
                    vhh = xb[(size_t)(yh * WW + xh) * CCH];
                } else {
                    vll = xb[yl * WW + xl];
                    vlh = xb[yl * WW + xh];
                    vhl = xb[yh * WW + xl];
                    vhh = xb[yh * WW + xh];
                }
                a += wy1 * (wx1 * vll + wx2 * vlh) + wy2 * (wx1 * vhl + wx2 * vhh);
            }
            acc[px] += a;
        }
    }

    float* op = out + ((size_t)r * CCH + c) * (POOL * POOL) + py * POOL;
    #pragma unroll
    for (int px = 0; px < POOL; ++px)
        op[px] = acc[px] * 0.25f;         // / (S*S)
}

extern "C" void kernel_launch(void* const* d_in, const int* in_sizes, int n_in,
                              void* d_out, int out_size, void* d_ws, size_t ws_size,
                              hipStream_t stream) {
    const float* x    = (const float*)d_in[0];
    const float* rois = (const float*)d_in[1];
    float*       out  = (float*)d_out;

    int R   = in_sizes[1] / 5;
    int nwg = R * POOL;

    size_t xt_bytes = (size_t)NN * HH * WW * CCH * sizeof(float);
    if (ws_size >= xt_bytes) {
        float* xt = (float*)d_ws;
        dim3 tg((HH * WW + 31) / 32, CCH / 32, NN);
        transpose_nchw_to_nhwc<<<tg, 256, 0, stream>>>(x, xt);
        roi_align_kernel<true><<<nwg, 256, 0, stream>>>(xt, rois, out, nwg);
    } else {
        roi_align_kernel<false><<<nwg, 256, 0, stream>>>(x, rois, out, nwg);
    }
}